// Round 8
// baseline (591.841 us; speedup 1.0000x reference)
//
#include <hip/hip_runtime.h>

#define D 128

typedef short short8_t __attribute__((ext_vector_type(8)));
typedef float float4_t __attribute__((ext_vector_type(4)));

// CSR-build bucketing: bucket = dst >> 8 (256 nodes/bucket), NB <= 512
#define BSH 8
#define BSZ 256
#define NBLK_A 256

// ---------------------------------------------------------------- bf16 helpers
__device__ __forceinline__ float bf_lo(unsigned u) { return __uint_as_float(u << 16); }
__device__ __forceinline__ float bf_hi(unsigned u) { return __uint_as_float(u & 0xffff0000u); }
__device__ __forceinline__ unsigned to_bf1(float x) {           // RNE round to bf16
    unsigned b = __float_as_uint(x);
    return (b + 0x7fffu + ((b >> 16) & 1u)) >> 16;
}
__device__ __forceinline__ unsigned pack2(float a, float b) {
    return to_bf1(a) | (to_bf1(b) << 16);
}

// ---------------------------------------------------------------- prep1 megakernel
// block ranges: [0,256) csr_hist | [256,2304) f32->bf16 | wpack | find_starts | reduce_lead
__global__ __launch_bounds__(256)
void prep1(const int* __restrict__ dst, int* __restrict__ Hist, int E_, int chunk,
           const float4* __restrict__ x4, uint2* __restrict__ xb2, long n4,
           const float* __restrict__ W, uint4* __restrict__ Wpk, int L_,
           const int* __restrict__ gids, int N_, const int* __restrict__ init_gid, int NI_,
           int G_, int* __restrict__ nstart, int* __restrict__ istart,
           const float* __restrict__ leadf, int NL_, float* __restrict__ hlead,
           int eb1, int eb2, int eb3) {
    int b = blockIdx.x, t = threadIdx.x;
    if (b < NBLK_A) {
        // ---- csr_hist
        __shared__ int h[512];
        h[t] = 0; h[t + 256] = 0;
        __syncthreads();
        int base = b * chunk;
        int end = base + chunk; if (end > E_) end = E_;
        for (int i = base + t; i < end; i += 256)
            atomicAdd(&h[dst[i] >> BSH], 1);
        __syncthreads();
        Hist[b * 512 + t] = h[t];
        Hist[b * 512 + t + 256] = h[t + 256];
    } else if (b < eb1) {
        // ---- f32 -> bf16 convert of x
        long i = (long)(b - NBLK_A) * 256 + t;
        long stride = (long)(eb1 - NBLK_A) * 256;
        for (; i < n4; i += stride) {
            float4 v = x4[i];
            xb2[i] = make_uint2(pack2(v.x, v.y), pack2(v.z, v.w));
        }
    } else if (b < eb2) {
        // ---- wpack: MFMA B-fragment stream
        int id = (b - eb1) * 256 + t;
        if (id < L_ * 2048) {
            int lane = id & 63, cc = (id >> 6) & 3, tt = (id >> 8) & 7, l = id >> 11;
            int n = tt * 16 + (lane & 15);
            int k0 = cc * 32 + (lane >> 4) * 8;
            const float* Wb = W + (long)l * D * D;
            unsigned u0 = pack2(Wb[(long)(k0 + 0) * D + n], Wb[(long)(k0 + 1) * D + n]);
            unsigned u1 = pack2(Wb[(long)(k0 + 2) * D + n], Wb[(long)(k0 + 3) * D + n]);
            unsigned u2 = pack2(Wb[(long)(k0 + 4) * D + n], Wb[(long)(k0 + 5) * D + n]);
            unsigned u3 = pack2(Wb[(long)(k0 + 6) * D + n], Wb[(long)(k0 + 7) * D + n]);
            Wpk[id] = make_uint4(u0, u1, u2, u3);
        }
    } else if (b < eb3) {
        // ---- find_starts for gids and init_gid
        int id = (b - eb2) * 256 + t;
        if (id < 2 * (G_ + 1)) {
            const int* arr; int n; int* outp; int g;
            if (id <= G_) { arr = gids; n = N_; outp = nstart; g = id; }
            else { arr = init_gid; n = NI_; outp = istart; g = id - (G_ + 1); }
            if (g == G_) outp[g] = n;
            else {
                int lo = 0, hi = n;
                while (lo < hi) { int mid = (lo + hi) >> 1; if (arr[mid] < g) lo = mid + 1; else hi = mid; }
                outp[g] = lo;
            }
        }
    } else {
        // ---- reduce_lead
        if (t < D) {
            float a0 = 0.f, a1 = 0.f, a2 = 0.f, a3 = 0.f;
            int r = 0;
            for (; r + 4 <= NL_; r += 4) {
                a0 += leadf[(long)r * D + t];
                a1 += leadf[(long)(r + 1) * D + t];
                a2 += leadf[(long)(r + 2) * D + t];
                a3 += leadf[(long)(r + 3) * D + t];
            }
            for (; r < NL_; ++r) a0 += leadf[(long)r * D + t];
            hlead[t] = a0 + a1 + a2 + a3;
        }
    }
}

// ---------------------------------------------------------------- CSR scans

__global__ __launch_bounds__(256)
void csr_scan_blocks(int* __restrict__ Hist, int* __restrict__ Tot) {
    __shared__ int sc[256];
    int bkt = blockIdx.x, t = threadIdx.x;
    int v = Hist[t * 512 + bkt];
    sc[t] = v; __syncthreads();
    for (int off = 1; off < 256; off <<= 1) {
        int u = (t >= off) ? sc[t - off] : 0;
        __syncthreads();
        sc[t] += u;
        __syncthreads();
    }
    Hist[t * 512 + bkt] = sc[t] - v;          // exclusive
    if (t == 255) Tot[bkt] = sc[255];
}

__global__ __launch_bounds__(512)
void csr_scan_base(const int* __restrict__ Tot, int* __restrict__ Base, int NB) {
    __shared__ int sc[512];
    int t = threadIdx.x;
    int v = (t < NB) ? Tot[t] : 0;
    sc[t] = v; __syncthreads();
    for (int off = 1; off < 512; off <<= 1) {
        int u = (t >= off) ? sc[t - off] : 0;
        __syncthreads();
        sc[t] += u;
        __syncthreads();
    }
    Base[t] = sc[t] - v;
    if (t == NB - 1) Base[NB] = sc[t];
}

// ---------------------------------------------------------------- phase3: scatter || cvec segsum
__global__ __launch_bounds__(256)
void phase3(const int* __restrict__ src, const int* __restrict__ dst,
            const int* __restrict__ Hist, const int* __restrict__ Base,
            unsigned* __restrict__ EdgeBuf, int E_, int chunk,
            const float* __restrict__ initf, const int* __restrict__ istart,
            const float* __restrict__ hlead, float* __restrict__ cvec, int G_) {
    int b = blockIdx.x, t = threadIdx.x;
    if (b < NBLK_A) {
        __shared__ int cur[512];
        cur[t]       = Base[t]       + Hist[b * 512 + t];
        cur[t + 256] = Base[t + 256] + Hist[b * 512 + t + 256];
        __syncthreads();
        int base = b * chunk;
        int end = base + chunk; if (end > E_) end = E_;
        for (int i = base + t; i < end; i += 256) {
            int s = src[i], dd = dst[i];
            int p = atomicAdd(&cur[dd >> BSH], 1);
            EdgeBuf[p] = (unsigned)s | ((unsigned)(dd & (BSZ - 1)) << 24);
        }
        return;
    }
    int g = b - NBLK_A;
    if (g >= G_) return;
    __shared__ float xs2[2][D];
    int col = t & 127, rp = t >> 7;
    int r0 = istart[g], r1 = istart[g + 1];
    float a0 = 0.f, a1 = 0.f, a2 = 0.f, a3 = 0.f;
    int r = r0 + rp;
    for (; r + 6 < r1; r += 8) {
        a0 += initf[(long)r * D + col];
        a1 += initf[(long)(r + 2) * D + col];
        a2 += initf[(long)(r + 4) * D + col];
        a3 += initf[(long)(r + 6) * D + col];
    }
    for (; r < r1; r += 2) a0 += initf[(long)r * D + col];
    xs2[rp][col] = (a0 + a1) + (a2 + a3);
    __syncthreads();
    if (t < D) cvec[(long)g * D + t] = xs2[0][t] + xs2[1][t] + hlead[t];
}

// ---------------------------------------------------------------- csr_fill
__global__ __launch_bounds__(256)
void csr_fill(const unsigned* __restrict__ EdgeBuf, const int* __restrict__ Base,
              int* __restrict__ rowptr, int* __restrict__ csr, int N_, int E_) {
    __shared__ int deg[256];
    __shared__ int cur[256];
    int b = blockIdx.x, t = threadIdx.x;
    int e0 = Base[b], e1 = Base[b + 1];
    deg[t] = 0;
    __syncthreads();
    for (int i = e0 + t; i < e1; i += 256)
        atomicAdd(&deg[EdgeBuf[i] >> 24], 1);
    __syncthreads();
    int v = deg[t];
    cur[t] = v; __syncthreads();
    for (int off = 1; off < 256; off <<= 1) {
        int u = (t >= off) ? cur[t - off] : 0;
        __syncthreads();
        cur[t] += u;
        __syncthreads();
    }
    int excl = cur[t] - v;
    int node = b * BSZ + t;
    if (node < N_) rowptr[node] = e0 + excl;
    cur[t] = e0 + excl;
    __syncthreads();
    for (int i = e0 + t; i < e1; i += 256) {
        unsigned ev = EdgeBuf[i];
        int p = atomicAdd(&cur[ev >> 24], 1);
        csr[p] = (int)(ev & 0x00FFFFFFu);
    }
    if (b == 0 && t == 0) rowptr[N_] = E_;
}

// ---------------------------------------------------------------- per-layer graph side
// T[g] = segsum_bf(h)[g] @ Wl + cvec[g] @ Wcl + bl   (R5-measured structure)
__global__ __launch_bounds__(128)
void graph_side(const unsigned* __restrict__ hb, const int* __restrict__ start,
                const float* __restrict__ cvec, const float* __restrict__ Wl,
                const float* __restrict__ Wcl, const float* __restrict__ bl,
                float* __restrict__ T) {
    __shared__ float xs[D];
    __shared__ float cs[D];
    int g = blockIdx.x, tid = threadIdx.x;
    int r0 = start[g], r1 = start[g + 1];
    int c = tid >> 1;
    bool hi = tid & 1;
    float a0=0,a1=0,a2=0,a3=0,a4=0,a5=0,a6=0,a7=0;
    int r = r0;
    for (; r + 8 <= r1; r += 8) {
        unsigned u0 = hb[(long)(r+0)*64+c], u1 = hb[(long)(r+1)*64+c];
        unsigned u2 = hb[(long)(r+2)*64+c], u3 = hb[(long)(r+3)*64+c];
        unsigned u4 = hb[(long)(r+4)*64+c], u5 = hb[(long)(r+5)*64+c];
        unsigned u6 = hb[(long)(r+6)*64+c], u7 = hb[(long)(r+7)*64+c];
        a0 += hi ? bf_hi(u0) : bf_lo(u0);
        a1 += hi ? bf_hi(u1) : bf_lo(u1);
        a2 += hi ? bf_hi(u2) : bf_lo(u2);
        a3 += hi ? bf_hi(u3) : bf_lo(u3);
        a4 += hi ? bf_hi(u4) : bf_lo(u4);
        a5 += hi ? bf_hi(u5) : bf_lo(u5);
        a6 += hi ? bf_hi(u6) : bf_lo(u6);
        a7 += hi ? bf_hi(u7) : bf_lo(u7);
    }
    for (; r < r1; ++r) {
        unsigned u = hb[(long)r*64+c];
        a0 += hi ? bf_hi(u) : bf_lo(u);
    }
    xs[tid] = ((a0+a1)+(a2+a3)) + ((a4+a5)+(a6+a7));
    cs[tid] = cvec[(long)g * D + tid];
    __syncthreads();
    float p0=0,p1=0,p2=0,p3=0;
    for (int k = 0; k < D; k += 4) {
        p0 += xs[k]   * Wl[(long)k*D + tid];
        p1 += xs[k+1] * Wl[(long)(k+1)*D + tid];
        p2 += xs[k+2] * Wl[(long)(k+2)*D + tid];
        p3 += xs[k+3] * Wl[(long)(k+3)*D + tid];
    }
    for (int k = 0; k < D; k += 4) {
        p0 += cs[k]   * Wcl[(long)k*D + tid];
        p1 += cs[k+1] * Wcl[(long)(k+1)*D + tid];
        p2 += cs[k+2] * Wcl[(long)(k+2)*D + tid];
        p3 += cs[k+3] * Wcl[(long)(k+3)*D + tid];
    }
    T[(long)g * D + tid] = bl[tid] + (p0 + p1) + (p2 + p3);
}

// ---------------------------------------------------------------- readout
__global__ __launch_bounds__(128)
void readout(const unsigned* __restrict__ hb, const int* __restrict__ start,
             const float* __restrict__ f1w, const float* __restrict__ f1b,
             const float* __restrict__ f2w, const float* __restrict__ f2b,
             float* __restrict__ out) {
    __shared__ float part[2][64][2];
    __shared__ float xs[D];
    __shared__ float zs[D];
    int g = blockIdx.x, t = threadIdx.x;
    int c = t & 63, half = t >> 6;
    int r0 = start[g], r1 = start[g + 1];
    float l0=0,h0=0,l1=0,h1=0;
    int r = r0 + half;
    for (; r + 2 < r1; r += 4) {
        unsigned a = hb[(long)r * 64 + c];
        unsigned bq = hb[(long)(r + 2) * 64 + c];
        l0 += bf_lo(a);  h0 += bf_hi(a);
        l1 += bf_lo(bq); h1 += bf_hi(bq);
    }
    if (r < r1) { unsigned a = hb[(long)r * 64 + c]; l0 += bf_lo(a); h0 += bf_hi(a); }
    part[half][c][0] = l0 + l1;
    part[half][c][1] = h0 + h1;
    __syncthreads();
    xs[t] = part[0][t >> 1][t & 1] + part[1][t >> 1][t & 1];
    __syncthreads();
    float p0=0,p1=0,p2=0,p3=0;
    for (int k = 0; k < D; k += 4) {
        p0 += xs[k]     * f1w[(long)k * D + t];
        p1 += xs[k + 1] * f1w[(long)(k + 1) * D + t];
        p2 += xs[k + 2] * f1w[(long)(k + 2) * D + t];
        p3 += xs[k + 3] * f1w[(long)(k + 3) * D + t];
    }
    zs[t] = fmaxf(f1b[t] + (p0 + p1) + (p2 + p3), 0.f);
    __syncthreads();
    float q0=0,q1=0,q2=0,q3=0;
    for (int k = 0; k < D; k += 4) {
        q0 += zs[k]     * f2w[(long)k * D + t];
        q1 += zs[k + 1] * f2w[(long)(k + 1) * D + t];
        q2 += zs[k + 2] * f2w[(long)(k + 2) * D + t];
        q3 += zs[k + 3] * f2w[(long)(k + 3) * D + t];
    }
    out[(long)g * D + t] = f2b[t] + (q0 + q1) + (q2 + q3);
}

// ---------------------------------------------------------------- fused GIN layer (bf16 h, MFMA)
#define TROWS 64
__global__ __launch_bounds__(256, 6)
void layer_kernel(const unsigned* __restrict__ hb, const uint4* __restrict__ Wpk_l,
                  const float* __restrict__ T, const int* __restrict__ gids,
                  const int* __restrict__ rowptr, const int* __restrict__ csr,
                  const float* __restrict__ eps_l, unsigned* __restrict__ houtb, int n) {
    __shared__ __align__(16) unsigned Minb[TROWS][68];
    int tid = threadIdx.x;
    int w = tid >> 6, lane = tid & 63;
    int w16 = w * 16;
    int rowBase = blockIdx.x * TROWS;
    int rb = rowBase + w16;
    float epsv = 1.0f + *eps_l;

    int rp = rb + lane; if (rp > n) rp = n;
    int evv = rowptr[rp];

    int e0 = __shfl(evv, 0);
    int e1 = __shfl(evv, 1);
    int idxv = (e0 + lane < e1) ? csr[e0 + lane] : 0;

    for (int i = 0; i < 16; ++i) {
        int r = rb + i;
        int deg = e1 - e0;
        int e0n = __shfl(evv, i + 1);
        int e1n = __shfl(evv, i + 2);
        int idxn = (e0n + lane < e1n) ? csr[e0n + lane] : 0;
        float sx = 0.f, sy = 0.f;
        if (r < n) {
            unsigned su = hb[(long)r * 64 + lane];
            float ax0 = epsv * bf_lo(su), ay0 = epsv * bf_hi(su);
            float ax1=0,ay1=0,ax2=0,ay2=0,ax3=0,ay3=0;
            int iv = idxv;
            int base = 0;
            while (true) {
                int m = deg - base; if (m > 64) m = 64;
                int j = 0;
                for (; j + 16 <= m; j += 16) {   // 16 loads in flight
                    int s0=__shfl(iv,j+0),  s1=__shfl(iv,j+1),  s2=__shfl(iv,j+2),  s3=__shfl(iv,j+3);
                    int s4=__shfl(iv,j+4),  s5=__shfl(iv,j+5),  s6=__shfl(iv,j+6),  s7=__shfl(iv,j+7);
                    int s8=__shfl(iv,j+8),  s9=__shfl(iv,j+9),  sA=__shfl(iv,j+10), sB=__shfl(iv,j+11);
                    int sC=__shfl(iv,j+12), sD=__shfl(iv,j+13), sE=__shfl(iv,j+14), sF=__shfl(iv,j+15);
                    unsigned u0=hb[(long)s0*64+lane], u1=hb[(long)s1*64+lane];
                    unsigned u2=hb[(long)s2*64+lane], u3=hb[(long)s3*64+lane];
                    unsigned u4=hb[(long)s4*64+lane], u5=hb[(long)s5*64+lane];
                    unsigned u6=hb[(long)s6*64+lane], u7=hb[(long)s7*64+lane];
                    unsigned u8=hb[(long)s8*64+lane], u9=hb[(long)s9*64+lane];
                    unsigned uA=hb[(long)sA*64+lane], uB=hb[(long)sB*64+lane];
                    unsigned uC=hb[(long)sC*64+lane], uD=hb[(long)sD*64+lane];
                    unsigned uE=hb[(long)sE*64+lane], uF=hb[(long)sF*64+lane];
                    ax0+=bf_lo(u0); ay0+=bf_hi(u0); ax1+=bf_lo(u1); ay1+=bf_hi(u1);
                    ax2+=bf_lo(u2); ay2+=bf_hi(u2); ax3+=bf_lo(u3); ay3+=bf_hi(u3);
                    ax0+=bf_lo(u4); ay0+=bf_hi(u4); ax1+=bf_lo(u5); ay1+=bf_hi(u5);
                    ax2+=bf_lo(u6); ay2+=bf_hi(u6); ax3+=bf_lo(u7); ay3+=bf_hi(u7);
                    ax0+=bf_lo(u8); ay0+=bf_hi(u8); ax1+=bf_lo(u9); ay1+=bf_hi(u9);
                    ax2+=bf_lo(uA); ay2+=bf_hi(uA); ax3+=bf_lo(uB); ay3+=bf_hi(uB);
                    ax0+=bf_lo(uC); ay0+=bf_hi(uC); ax1+=bf_lo(uD); ay1+=bf_hi(uD);
                    ax2+=bf_lo(uE); ay2+=bf_hi(uE); ax3+=bf_lo(uF); ay3+=bf_hi(uF);
                }
                for (; j + 8 <= m; j += 8) {
                    int s0=__shfl(iv,j+0), s1=__shfl(iv,j+1), s2=__shfl(iv,j+2), s3=__shfl(iv,j+3);
                    int s4=__shfl(iv,j+4), s5=__shfl(iv,j+5), s6=__shfl(iv,j+6), s7=__shfl(iv,j+7);
                    unsigned u0=hb[(long)s0*64+lane], u1=hb[(long)s1*64+lane];
                    unsigned u2=hb[(long)s2*64+lane], u3=hb[(long)s3*64+lane];
                    unsigned u4=hb[(long)s4*64+lane], u5=hb[(long)s5*64+lane];
                    unsigned u6=hb[(long)s6*64+lane], u7=hb[(long)s7*64+lane];
                    ax0+=bf_lo(u0); ay0+=bf_hi(u0); ax1+=bf_lo(u1); ay1+=bf_hi(u1);
                    ax2+=bf_lo(u2); ay2+=bf_hi(u2); ax3+=bf_lo(u3); ay3+=bf_hi(u3);
                    ax0+=bf_lo(u4); ay0+=bf_hi(u4); ax1+=bf_lo(u5); ay1+=bf_hi(u5);
                    ax2+=bf_lo(u6); ay2+=bf_hi(u6); ax3+=bf_lo(u7); ay3+=bf_hi(u7);
                }
                for (; j < m; ++j) {
                    int s = __shfl(iv, j);
                    unsigned u = hb[(long)s * 64 + lane];
                    ax0 += bf_lo(u); ay0 += bf_hi(u);
                }
                base += 64;
                if (base >= deg) break;
                int mm = deg - base;
                iv = (lane < mm) ? csr[e0 + base + lane] : 0;
            }
            sx = (ax0 + ax1) + (ax2 + ax3);
            sy = (ay0 + ay1) + (ay2 + ay3);
        }
        Minb[w16 + i][lane] = pack2(sx, sy);
        e0 = e0n; e1 = e1n; idxv = idxn;
    }
    // No barrier: each wave's rows are private.

    int m_ = lane & 15, quad = lane >> 4;
    float4_t acc[8];
    #pragma unroll
    for (int tt = 0; tt < 8; ++tt) { acc[tt][0]=0.f; acc[tt][1]=0.f; acc[tt][2]=0.f; acc[tt][3]=0.f; }

    #pragma unroll
    for (int cc = 0; cc < 4; ++cc) {
        short8_t af = *(const short8_t*)&Minb[w16 + m_][cc * 16 + quad * 4];
        #pragma unroll
        for (int tt = 0; tt < 8; ++tt) {
            short8_t bf = *(const short8_t*)&Wpk_l[(tt * 4 + cc) * 64 + lane];
            acc[tt] = __builtin_amdgcn_mfma_f32_16x16x32_bf16(af, bf, acc[tt], 0, 0, 0);
        }
    }

    int gq[4];
    #pragma unroll
    for (int reg = 0; reg < 4; ++reg) {
        int r = rb + quad * 4 + reg;
        gq[reg] = (r < n) ? gids[r] : 0;
    }
    #pragma unroll
    for (int tt = 0; tt < 8; ++tt) {
        int col = tt * 16 + m_;
        #pragma unroll
        for (int reg = 0; reg < 4; ++reg) {
            float v = acc[tt][reg] + T[(long)gq[reg] * D + col];
            v = fmaxf(v, 0.f);
            float v2 = __shfl_xor(v, 1);
            if (!(lane & 1)) Minb[w16 + quad * 4 + reg][tt * 8 + (m_ >> 1)] = pack2(v, v2);
        }
    }
    #pragma unroll
    for (int rr = 0; rr < 4; ++rr) {
        int lrow = rr * 4 + (lane >> 4);
        int r = rowBase + w16 + lrow;
        if (r < n) {
            uint4 v = *(const uint4*)&Minb[w16 + lrow][(lane & 15) * 4];
            *(uint4*)&houtb[(long)r * 64 + (lane & 15) * 4] = v;
        }
    }
}

// ---------------------------------------------------------------- launch

static inline size_t align512(size_t x) { return (x + 511) & ~(size_t)511; }

extern "C" void kernel_launch(void* const* d_in, const int* in_sizes, int n_in,
                              void* d_out, int out_size, void* d_ws, size_t ws_size,
                              hipStream_t stream) {
    const float* x        = (const float*)d_in[0];
    const int*   src      = (const int*)d_in[1];
    const int*   dst      = (const int*)d_in[2];
    const int*   gids     = (const int*)d_in[3];
    const float* initf    = (const float*)d_in[4];
    const int*   init_gid = (const int*)d_in[5];
    const float* leadf    = (const float*)d_in[6];
    const float* W        = (const float*)d_in[7];
    const float* Wc       = (const float*)d_in[8];
    const float* b        = (const float*)d_in[9];
    const float* eps      = (const float*)d_in[10];
    const float* fc1_w    = (const float*)d_in[11];
    const float* fc1_b    = (const float*)d_in[12];
    const float* fc2_w    = (const float*)d_in[13];
    const float* fc2_b    = (const float*)d_in[14];
    float* out = (float*)d_out;

    const int N  = in_sizes[0] / D;
    const int E  = in_sizes[1];
    const int NI = in_sizes[4] / D;
    const int NL = in_sizes[6] / D;
    const int L  = in_sizes[10];
    const int C  = in_sizes[13] / D;
    const int G  = out_size / C;

    // workspace carve-up
    char* p = (char*)d_ws;
    unsigned* xb  = (unsigned*)p; p += align512((size_t)N * 64 * 4);
    unsigned* hAb = (unsigned*)p; p += align512((size_t)N * 64 * 4);
    unsigned* hBb = (unsigned*)p; p += align512((size_t)N * 64 * 4);
    float* T     = (float*)p; p += align512((size_t)G * D * 4);
    float* cvec  = (float*)p; p += align512((size_t)G * D * 4);
    float* hlead = (float*)p; p += align512((size_t)D * 4);
    int* rowptr  = (int*)p;   p += align512((size_t)(N + 1) * 4);
    int* csr     = (int*)p;   p += align512((size_t)E * 4);
    unsigned* EdgeBuf = (unsigned*)p; p += align512((size_t)E * 4);
    int* Hist    = (int*)p;   p += align512((size_t)NBLK_A * 512 * 4);
    int* Tot     = (int*)p;   p += align512((size_t)520 * 4);
    int* Base    = (int*)p;   p += align512((size_t)520 * 4);
    int* nstart  = (int*)p;   p += align512((size_t)(G + 1) * 4);
    int* istart  = (int*)p;   p += align512((size_t)(G + 1) * 4);
    uint4* Wpk   = (uint4*)p; p += align512((size_t)L * 2048 * 16);
    (void)ws_size; (void)n_in;

    const int NB = (N + BSZ - 1) / BSZ;
    const int chunk = (E + NBLK_A - 1) / NBLK_A;

    // prep1 block-range layout
    const int CVB = 2048;                                  // convert blocks
    const int WPB = (L * 2048 + 255) / 256;
    const int STB = (2 * (G + 1) + 255) / 256;
    const int eb1 = NBLK_A + CVB;
    const int eb2 = eb1 + WPB;
    const int eb3 = eb2 + STB;
    const int prepBlocks = eb3 + 1;

    // 1: hist || bf16-convert || wpack || find_starts || reduce_lead
    prep1<<<prepBlocks, 256, 0, stream>>>(dst, Hist, E, chunk,
                                          (const float4*)x, (uint2*)xb, (long)N * D / 4,
                                          W, Wpk, L,
                                          gids, N, init_gid, NI, G, nstart, istart,
                                          leadf, NL, hlead, eb1, eb2, eb3);
    // 2-3: scans
    csr_scan_blocks<<<NB, 256, 0, stream>>>(Hist, Tot);
    csr_scan_base<<<1, 512, 0, stream>>>(Tot, Base, NB);
    // 4: scatter || cvec segsum
    phase3<<<NBLK_A + G, 256, 0, stream>>>(src, dst, Hist, Base, EdgeBuf, E, chunk,
                                           initf, istart, hlead, cvec, G);
    // 5: per-bucket CSR fill
    csr_fill<<<NB, 256, 0, stream>>>(EdgeBuf, Base, rowptr, csr, N, E);

    const unsigned* hcur = xb;
    unsigned* bufs[2] = { hAb, hBb };
    int layerBlocks = (N + TROWS - 1) / TROWS;
    for (int l = 0; l < L; ++l) {
        graph_side<<<G, D, 0, stream>>>(hcur, nstart, cvec, W + (long)l * D * D,
                                        Wc + (long)l * D * D, b + (long)l * D, T);
        unsigned* hnext = bufs[l & 1];
        layer_kernel<<<layerBlocks, 256, 0, stream>>>(hcur, Wpk + (size_t)l * 2048, T,
                                                      gids, rowptr, csr,
                                                      eps + l, hnext, N);
        hcur = hnext;
    }

    // readout
    readout<<<G, D, 0, stream>>>(hcur, nstart, fc1_w, fc1_b, fc2_w, fc2_b, out);
}

// Round 9
// 491.137 us; speedup vs baseline: 1.2050x; 1.2050x over previous
//
#include <hip/hip_runtime.h>

#define D 128

typedef short short8_t __attribute__((ext_vector_type(8)));
typedef float float4_t __attribute__((ext_vector_type(4)));

// CSR-build bucketing: bucket = dst >> 8 (256 nodes/bucket), NB <= 512
#define BSH 8
#define BSZ 256
#define NBLK_A 256

// ---------------------------------------------------------------- bf16 helpers
__device__ __forceinline__ float bf_lo(unsigned u) { return __uint_as_float(u << 16); }
__device__ __forceinline__ float bf_hi(unsigned u) { return __uint_as_float(u & 0xffff0000u); }
__device__ __forceinline__ unsigned to_bf1(float x) {           // RNE round to bf16
    unsigned b = __float_as_uint(x);
    return (b + 0x7fffu + ((b >> 16) & 1u)) >> 16;
}
__device__ __forceinline__ unsigned pack2(float a, float b) {
    return to_bf1(a) | (to_bf1(b) << 16);
}

// ---------------------------------------------------------------- prep1 megakernel
// block ranges: [0,256) csr_hist | f32->bf16 | wpack | find_starts | reduce_lead
__global__ __launch_bounds__(256)
void prep1(const int* __restrict__ dst, int* __restrict__ Hist, int E_, int chunk,
           const float4* __restrict__ x4, uint2* __restrict__ xb2, long n4,
           const float* __restrict__ W, uint4* __restrict__ Wpk, int L_,
           const int* __restrict__ gids, int N_, const int* __restrict__ init_gid, int NI_,
           int G_, int* __restrict__ nstart, int* __restrict__ istart,
           const float* __restrict__ leadf, int NL_, float* __restrict__ hlead,
           int eb1, int eb2, int eb3) {
    int b = blockIdx.x, t = threadIdx.x;
    if (b < NBLK_A) {
        // ---- csr_hist
        __shared__ int h[512];
        h[t] = 0; h[t + 256] = 0;
        __syncthreads();
        int base = b * chunk;
        int end = base + chunk; if (end > E_) end = E_;
        for (int i = base + t; i < end; i += 256)
            atomicAdd(&h[dst[i] >> BSH], 1);
        __syncthreads();
        Hist[b * 512 + t] = h[t];
        Hist[b * 512 + t + 256] = h[t + 256];
    } else if (b < eb1) {
        // ---- f32 -> bf16 convert of x
        long i = (long)(b - NBLK_A) * 256 + t;
        long stride = (long)(eb1 - NBLK_A) * 256;
        for (; i < n4; i += stride) {
            float4 v = x4[i];
            xb2[i] = make_uint2(pack2(v.x, v.y), pack2(v.z, v.w));
        }
    } else if (b < eb2) {
        // ---- wpack: MFMA B-fragment stream
        int id = (b - eb1) * 256 + t;
        if (id < L_ * 2048) {
            int lane = id & 63, cc = (id >> 6) & 3, tt = (id >> 8) & 7, l = id >> 11;
            int n = tt * 16 + (lane & 15);
            int k0 = cc * 32 + (lane >> 4) * 8;
            const float* Wb = W + (long)l * D * D;
            unsigned u0 = pack2(Wb[(long)(k0 + 0) * D + n], Wb[(long)(k0 + 1) * D + n]);
            unsigned u1 = pack2(Wb[(long)(k0 + 2) * D + n], Wb[(long)(k0 + 3) * D + n]);
            unsigned u2 = pack2(Wb[(long)(k0 + 4) * D + n], Wb[(long)(k0 + 5) * D + n]);
            unsigned u3 = pack2(Wb[(long)(k0 + 6) * D + n], Wb[(long)(k0 + 7) * D + n]);
            Wpk[id] = make_uint4(u0, u1, u2, u3);
        }
    } else if (b < eb3) {
        // ---- find_starts for gids and init_gid
        int id = (b - eb2) * 256 + t;
        if (id < 2 * (G_ + 1)) {
            const int* arr; int n; int* outp; int g;
            if (id <= G_) { arr = gids; n = N_; outp = nstart; g = id; }
            else { arr = init_gid; n = NI_; outp = istart; g = id - (G_ + 1); }
            if (g == G_) outp[g] = n;
            else {
                int lo = 0, hi = n;
                while (lo < hi) { int mid = (lo + hi) >> 1; if (arr[mid] < g) lo = mid + 1; else hi = mid; }
                outp[g] = lo;
            }
        }
    } else {
        // ---- reduce_lead
        if (t < D) {
            float a0 = 0.f, a1 = 0.f, a2 = 0.f, a3 = 0.f;
            int r = 0;
            for (; r + 4 <= NL_; r += 4) {
                a0 += leadf[(long)r * D + t];
                a1 += leadf[(long)(r + 1) * D + t];
                a2 += leadf[(long)(r + 2) * D + t];
                a3 += leadf[(long)(r + 3) * D + t];
            }
            for (; r < NL_; ++r) a0 += leadf[(long)r * D + t];
            hlead[t] = a0 + a1 + a2 + a3;
        }
    }
}

// ---------------------------------------------------------------- CSR scans

__global__ __launch_bounds__(256)
void csr_scan_blocks(int* __restrict__ Hist, int* __restrict__ Tot) {
    __shared__ int sc[256];
    int bkt = blockIdx.x, t = threadIdx.x;
    int v = Hist[t * 512 + bkt];
    sc[t] = v; __syncthreads();
    for (int off = 1; off < 256; off <<= 1) {
        int u = (t >= off) ? sc[t - off] : 0;
        __syncthreads();
        sc[t] += u;
        __syncthreads();
    }
    Hist[t * 512 + bkt] = sc[t] - v;          // exclusive
    if (t == 255) Tot[bkt] = sc[255];
}

__global__ __launch_bounds__(512)
void csr_scan_base(const int* __restrict__ Tot, int* __restrict__ Base, int NB) {
    __shared__ int sc[512];
    int t = threadIdx.x;
    int v = (t < NB) ? Tot[t] : 0;
    sc[t] = v; __syncthreads();
    for (int off = 1; off < 512; off <<= 1) {
        int u = (t >= off) ? sc[t - off] : 0;
        __syncthreads();
        sc[t] += u;
        __syncthreads();
    }
    Base[t] = sc[t] - v;
    if (t == NB - 1) Base[NB] = sc[t];
}

// ---------------------------------------------------------------- phase3: scatter || cvec segsum
__global__ __launch_bounds__(256)
void phase3(const int* __restrict__ src, const int* __restrict__ dst,
            const int* __restrict__ Hist, const int* __restrict__ Base,
            unsigned* __restrict__ EdgeBuf, int E_, int chunk,
            const float* __restrict__ initf, const int* __restrict__ istart,
            const float* __restrict__ hlead, float* __restrict__ cvec, int G_) {
    int b = blockIdx.x, t = threadIdx.x;
    if (b < NBLK_A) {
        __shared__ int cur[512];
        cur[t]       = Base[t]       + Hist[b * 512 + t];
        cur[t + 256] = Base[t + 256] + Hist[b * 512 + t + 256];
        __syncthreads();
        int base = b * chunk;
        int end = base + chunk; if (end > E_) end = E_;
        for (int i = base + t; i < end; i += 256) {
            int s = src[i], dd = dst[i];
            int p = atomicAdd(&cur[dd >> BSH], 1);
            EdgeBuf[p] = (unsigned)s | ((unsigned)(dd & (BSZ - 1)) << 24);
        }
        return;
    }
    int g = b - NBLK_A;
    if (g >= G_) return;
    __shared__ float xs2[2][D];
    int col = t & 127, rp = t >> 7;
    int r0 = istart[g], r1 = istart[g + 1];
    float a0 = 0.f, a1 = 0.f, a2 = 0.f, a3 = 0.f;
    int r = r0 + rp;
    for (; r + 6 < r1; r += 8) {
        a0 += initf[(long)r * D + col];
        a1 += initf[(long)(r + 2) * D + col];
        a2 += initf[(long)(r + 4) * D + col];
        a3 += initf[(long)(r + 6) * D + col];
    }
    for (; r < r1; r += 2) a0 += initf[(long)r * D + col];
    xs2[rp][col] = (a0 + a1) + (a2 + a3);
    __syncthreads();
    if (t < D) cvec[(long)g * D + t] = xs2[0][t] + xs2[1][t] + hlead[t];
}

// ---------------------------------------------------------------- csr_fill
__global__ __launch_bounds__(256)
void csr_fill(const unsigned* __restrict__ EdgeBuf, const int* __restrict__ Base,
              int* __restrict__ rowptr, int* __restrict__ csr, int N_, int E_) {
    __shared__ int deg[256];
    __shared__ int cur[256];
    int b = blockIdx.x, t = threadIdx.x;
    int e0 = Base[b], e1 = Base[b + 1];
    deg[t] = 0;
    __syncthreads();
    for (int i = e0 + t; i < e1; i += 256)
        atomicAdd(&deg[EdgeBuf[i] >> 24], 1);
    __syncthreads();
    int v = deg[t];
    cur[t] = v; __syncthreads();
    for (int off = 1; off < 256; off <<= 1) {
        int u = (t >= off) ? cur[t - off] : 0;
        __syncthreads();
        cur[t] += u;
        __syncthreads();
    }
    int excl = cur[t] - v;
    int node = b * BSZ + t;
    if (node < N_) rowptr[node] = e0 + excl;
    cur[t] = e0 + excl;
    __syncthreads();
    for (int i = e0 + t; i < e1; i += 256) {
        unsigned ev = EdgeBuf[i];
        int p = atomicAdd(&cur[ev >> 24], 1);
        csr[p] = (int)(ev & 0x00FFFFFFu);
    }
    if (b == 0 && t == 0) rowptr[N_] = E_;
}

// ---------------------------------------------------------------- per-layer graph side
// T[g] = segsum_bf(h)[g] @ Wl + cvec[g] @ Wcl + bl
__global__ __launch_bounds__(128)
void graph_side(const unsigned* __restrict__ hb, const int* __restrict__ start,
                const float* __restrict__ cvec, const float* __restrict__ Wl,
                const float* __restrict__ Wcl, const float* __restrict__ bl,
                float* __restrict__ T) {
    __shared__ float xs[D];
    __shared__ float cs[D];
    int g = blockIdx.x, tid = threadIdx.x;
    int r0 = start[g], r1 = start[g + 1];
    int c = tid >> 1;
    bool hi = tid & 1;
    float a0=0,a1=0,a2=0,a3=0,a4=0,a5=0,a6=0,a7=0;
    int r = r0;
    for (; r + 8 <= r1; r += 8) {
        unsigned u0 = hb[(long)(r+0)*64+c], u1 = hb[(long)(r+1)*64+c];
        unsigned u2 = hb[(long)(r+2)*64+c], u3 = hb[(long)(r+3)*64+c];
        unsigned u4 = hb[(long)(r+4)*64+c], u5 = hb[(long)(r+5)*64+c];
        unsigned u6 = hb[(long)(r+6)*64+c], u7 = hb[(long)(r+7)*64+c];
        a0 += hi ? bf_hi(u0) : bf_lo(u0);
        a1 += hi ? bf_hi(u1) : bf_lo(u1);
        a2 += hi ? bf_hi(u2) : bf_lo(u2);
        a3 += hi ? bf_hi(u3) : bf_lo(u3);
        a4 += hi ? bf_hi(u4) : bf_lo(u4);
        a5 += hi ? bf_hi(u5) : bf_lo(u5);
        a6 += hi ? bf_hi(u6) : bf_lo(u6);
        a7 += hi ? bf_hi(u7) : bf_lo(u7);
    }
    for (; r < r1; ++r) {
        unsigned u = hb[(long)r*64+c];
        a0 += hi ? bf_hi(u) : bf_lo(u);
    }
    xs[tid] = ((a0+a1)+(a2+a3)) + ((a4+a5)+(a6+a7));
    cs[tid] = cvec[(long)g * D + tid];
    __syncthreads();
    float p0=0,p1=0,p2=0,p3=0;
    for (int k = 0; k < D; k += 4) {
        p0 += xs[k]   * Wl[(long)k*D + tid];
        p1 += xs[k+1] * Wl[(long)(k+1)*D + tid];
        p2 += xs[k+2] * Wl[(long)(k+2)*D + tid];
        p3 += xs[k+3] * Wl[(long)(k+3)*D + tid];
    }
    for (int k = 0; k < D; k += 4) {
        p0 += cs[k]   * Wcl[(long)k*D + tid];
        p1 += cs[k+1] * Wcl[(long)(k+1)*D + tid];
        p2 += cs[k+2] * Wcl[(long)(k+2)*D + tid];
        p3 += cs[k+3] * Wcl[(long)(k+3)*D + tid];
    }
    T[(long)g * D + tid] = bl[tid] + (p0 + p1) + (p2 + p3);
}

// ---------------------------------------------------------------- readout
__global__ __launch_bounds__(128)
void readout(const unsigned* __restrict__ hb, const int* __restrict__ start,
             const float* __restrict__ f1w, const float* __restrict__ f1b,
             const float* __restrict__ f2w, const float* __restrict__ f2b,
             float* __restrict__ out) {
    __shared__ float part[2][64][2];
    __shared__ float xs[D];
    __shared__ float zs[D];
    int g = blockIdx.x, t = threadIdx.x;
    int c = t & 63, half = t >> 6;
    int r0 = start[g], r1 = start[g + 1];
    float l0=0,h0=0,l1=0,h1=0;
    int r = r0 + half;
    for (; r + 2 < r1; r += 4) {
        unsigned a = hb[(long)r * 64 + c];
        unsigned bq = hb[(long)(r + 2) * 64 + c];
        l0 += bf_lo(a);  h0 += bf_hi(a);
        l1 += bf_lo(bq); h1 += bf_hi(bq);
    }
    if (r < r1) { unsigned a = hb[(long)r * 64 + c]; l0 += bf_lo(a); h0 += bf_hi(a); }
    part[half][c][0] = l0 + l1;
    part[half][c][1] = h0 + h1;
    __syncthreads();
    xs[t] = part[0][t >> 1][t & 1] + part[1][t >> 1][t & 1];
    __syncthreads();
    float p0=0,p1=0,p2=0,p3=0;
    for (int k = 0; k < D; k += 4) {
        p0 += xs[k]     * f1w[(long)k * D + t];
        p1 += xs[k + 1] * f1w[(long)(k + 1) * D + t];
        p2 += xs[k + 2] * f1w[(long)(k + 2) * D + t];
        p3 += xs[k + 3] * f1w[(long)(k + 3) * D + t];
    }
    zs[t] = fmaxf(f1b[t] + (p0 + p1) + (p2 + p3), 0.f);
    __syncthreads();
    float q0=0,q1=0,q2=0,q3=0;
    for (int k = 0; k < D; k += 4) {
        q0 += zs[k]     * f2w[(long)k * D + t];
        q1 += zs[k + 1] * f2w[(long)(k + 1) * D + t];
        q2 += zs[k + 2] * f2w[(long)(k + 2) * D + t];
        q3 += zs[k + 3] * f2w[(long)(k + 3) * D + t];
    }
    out[(long)g * D + t] = f2b[t] + (q0 + q1) + (q2 + q3);
}

// ---------------------------------------------------------------- fused GIN layer (bf16 h, MFMA)
// R5-measured version (77.5 us): TROWS 64, 256 threads, 8-deep gather unroll.
#define TROWS 64
__global__ __launch_bounds__(256, 6)
void layer_kernel(const unsigned* __restrict__ hb, const uint4* __restrict__ Wpk_l,
                  const float* __restrict__ T, const int* __restrict__ gids,
                  const int* __restrict__ rowptr, const int* __restrict__ csr,
                  const float* __restrict__ eps_l, unsigned* __restrict__ houtb, int n) {
    __shared__ __align__(16) unsigned Minb[TROWS][68];
    int tid = threadIdx.x;
    int w = tid >> 6, lane = tid & 63;
    int w16 = w * 16;
    int rowBase = blockIdx.x * TROWS;
    int rb = rowBase + w16;
    float epsv = 1.0f + *eps_l;

    int rp = rb + lane; if (rp > n) rp = n;
    int evv = rowptr[rp];

    int e0 = __shfl(evv, 0);
    int e1 = __shfl(evv, 1);
    int idxv = (e0 + lane < e1) ? csr[e0 + lane] : 0;

    for (int i = 0; i < 16; ++i) {
        int r = rb + i;
        int deg = e1 - e0;
        int e0n = __shfl(evv, i + 1);
        int e1n = __shfl(evv, i + 2);
        int idxn = (e0n + lane < e1n) ? csr[e0n + lane] : 0;
        float sx = 0.f, sy = 0.f;
        if (r < n) {
            unsigned su = hb[(long)r * 64 + lane];
            float ax0 = epsv * bf_lo(su), ay0 = epsv * bf_hi(su);
            float ax1=0,ay1=0,ax2=0,ay2=0,ax3=0,ay3=0;
            int iv = idxv;
            int base = 0;
            while (true) {
                int m = deg - base; if (m > 64) m = 64;
                int j = 0;
                for (; j + 8 <= m; j += 8) {
                    int s0=__shfl(iv,j+0), s1=__shfl(iv,j+1), s2=__shfl(iv,j+2), s3=__shfl(iv,j+3);
                    int s4=__shfl(iv,j+4), s5=__shfl(iv,j+5), s6=__shfl(iv,j+6), s7=__shfl(iv,j+7);
                    unsigned u0=hb[(long)s0*64+lane], u1=hb[(long)s1*64+lane];
                    unsigned u2=hb[(long)s2*64+lane], u3=hb[(long)s3*64+lane];
                    unsigned u4=hb[(long)s4*64+lane], u5=hb[(long)s5*64+lane];
                    unsigned u6=hb[(long)s6*64+lane], u7=hb[(long)s7*64+lane];
                    ax0+=bf_lo(u0); ay0+=bf_hi(u0); ax1+=bf_lo(u1); ay1+=bf_hi(u1);
                    ax2+=bf_lo(u2); ay2+=bf_hi(u2); ax3+=bf_lo(u3); ay3+=bf_hi(u3);
                    ax0+=bf_lo(u4); ay0+=bf_hi(u4); ax1+=bf_lo(u5); ay1+=bf_hi(u5);
                    ax2+=bf_lo(u6); ay2+=bf_hi(u6); ax3+=bf_lo(u7); ay3+=bf_hi(u7);
                }
                for (; j < m; ++j) {
                    int s = __shfl(iv, j);
                    unsigned u = hb[(long)s * 64 + lane];
                    ax0 += bf_lo(u); ay0 += bf_hi(u);
                }
                base += 64;
                if (base >= deg) break;
                int mm = deg - base;
                iv = (lane < mm) ? csr[e0 + base + lane] : 0;
            }
            sx = (ax0 + ax1) + (ax2 + ax3);
            sy = (ay0 + ay1) + (ay2 + ay3);
        }
        Minb[w16 + i][lane] = pack2(sx, sy);
        e0 = e0n; e1 = e1n; idxv = idxn;
    }
    // No barrier: each wave's rows are private.

    int m_ = lane & 15, quad = lane >> 4;
    float4_t acc[8];
    #pragma unroll
    for (int tt = 0; tt < 8; ++tt) { acc[tt][0]=0.f; acc[tt][1]=0.f; acc[tt][2]=0.f; acc[tt][3]=0.f; }

    #pragma unroll
    for (int cc = 0; cc < 4; ++cc) {
        short8_t af = *(const short8_t*)&Minb[w16 + m_][cc * 16 + quad * 4];
        #pragma unroll
        for (int tt = 0; tt < 8; ++tt) {
            short8_t bf = *(const short8_t*)&Wpk_l[(tt * 4 + cc) * 64 + lane];
            acc[tt] = __builtin_amdgcn_mfma_f32_16x16x32_bf16(af, bf, acc[tt], 0, 0, 0);
        }
    }

    int gq[4];
    #pragma unroll
    for (int reg = 0; reg < 4; ++reg) {
        int r = rb + quad * 4 + reg;
        gq[reg] = (r < n) ? gids[r] : 0;
    }
    #pragma unroll
    for (int tt = 0; tt < 8; ++tt) {
        int col = tt * 16 + m_;
        #pragma unroll
        for (int reg = 0; reg < 4; ++reg) {
            float v = acc[tt][reg] + T[(long)gq[reg] * D + col];
            v = fmaxf(v, 0.f);
            float v2 = __shfl_xor(v, 1);
            if (!(lane & 1)) Minb[w16 + quad * 4 + reg][tt * 8 + (m_ >> 1)] = pack2(v, v2);
        }
    }
    #pragma unroll
    for (int rr = 0; rr < 4; ++rr) {
        int lrow = rr * 4 + (lane >> 4);
        int r = rowBase + w16 + lrow;
        if (r < n) {
            uint4 v = *(const uint4*)&Minb[w16 + lrow][(lane & 15) * 4];
            *(uint4*)&houtb[(long)r * 64 + (lane & 15) * 4] = v;
        }
    }
}

// ---------------------------------------------------------------- launch

static inline size_t align512(size_t x) { return (x + 511) & ~(size_t)511; }

extern "C" void kernel_launch(void* const* d_in, const int* in_sizes, int n_in,
                              void* d_out, int out_size, void* d_ws, size_t ws_size,
                              hipStream_t stream) {
    const float* x        = (const float*)d_in[0];
    const int*   src      = (const int*)d_in[1];
    const int*   dst      = (const int*)d_in[2];
    const int*   gids     = (const int*)d_in[3];
    const float* initf    = (const float*)d_in[4];
    const int*   init_gid = (const int*)d_in[5];
    const float* leadf    = (const float*)d_in[6];
    const float* W        = (const float*)d_in[7];
    const float* Wc       = (const float*)d_in[8];
    const float* b        = (const float*)d_in[9];
    const float* eps      = (const float*)d_in[10];
    const float* fc1_w    = (const float*)d_in[11];
    const float* fc1_b    = (const float*)d_in[12];
    const float* fc2_w    = (const float*)d_in[13];
    const float* fc2_b    = (const float*)d_in[14];
    float* out = (float*)d_out;

    const int N  = in_sizes[0] / D;
    const int E  = in_sizes[1];
    const int NI = in_sizes[4] / D;
    const int NL = in_sizes[6] / D;
    const int L  = in_sizes[10];
    const int C  = in_sizes[13] / D;
    const int G  = out_size / C;

    // workspace carve-up
    char* p = (char*)d_ws;
    unsigned* xb  = (unsigned*)p; p += align512((size_t)N * 64 * 4);
    unsigned* hAb = (unsigned*)p; p += align512((size_t)N * 64 * 4);
    unsigned* hBb = (unsigned*)p; p += align512((size_t)N * 64 * 4);
    float* T     = (float*)p; p += align512((size_t)G * D * 4);
    float* cvec  = (float*)p; p += align512((size_t)G * D * 4);
    float* hlead = (float*)p; p += align512((size_t)D * 4);
    int* rowptr  = (int*)p;   p += align512((size_t)(N + 1) * 4);
    int* csr     = (int*)p;   p += align512((size_t)E * 4);
    unsigned* EdgeBuf = (unsigned*)p; p += align512((size_t)E * 4);
    int* Hist    = (int*)p;   p += align512((size_t)NBLK_A * 512 * 4);
    int* Tot     = (int*)p;   p += align512((size_t)520 * 4);
    int* Base    = (int*)p;   p += align512((size_t)520 * 4);
    int* nstart  = (int*)p;   p += align512((size_t)(G + 1) * 4);
    int* istart  = (int*)p;   p += align512((size_t)(G + 1) * 4);
    uint4* Wpk   = (uint4*)p; p += align512((size_t)L * 2048 * 16);
    (void)ws_size; (void)n_in;

    const int NB = (N + BSZ - 1) / BSZ;
    const int chunk = (E + NBLK_A - 1) / NBLK_A;

    // prep1 block-range layout
    const int CVB = 2048;                                  // convert blocks
    const int WPB = (L * 2048 + 255) / 256;
    const int STB = (2 * (G + 1) + 255) / 256;
    const int eb1 = NBLK_A + CVB;
    const int eb2 = eb1 + WPB;
    const int eb3 = eb2 + STB;
    const int prepBlocks = eb3 + 1;

    // 1: hist || bf16-convert || wpack || find_starts || reduce_lead
    prep1<<<prepBlocks, 256, 0, stream>>>(dst, Hist, E, chunk,
                                          (const float4*)x, (uint2*)xb, (long)N * D / 4,
                                          W, Wpk, L,
                                          gids, N, init_gid, NI, G, nstart, istart,
                                          leadf, NL, hlead, eb1, eb2, eb3);
    // 2-3: scans
    csr_scan_blocks<<<NB, 256, 0, stream>>>(Hist, Tot);
    csr_scan_base<<<1, 512, 0, stream>>>(Tot, Base, NB);
    // 4: scatter || cvec segsum
    phase3<<<NBLK_A + G, 256, 0, stream>>>(src, dst, Hist, Base, EdgeBuf, E, chunk,
                                           initf, istart, hlead, cvec, G);
    // 5: per-bucket CSR fill
    csr_fill<<<NB, 256, 0, stream>>>(EdgeBuf, Base, rowptr, csr, N, E);

    const unsigned* hcur = xb;
    unsigned* bufs[2] = { hAb, hBb };
    int layerBlocks = (N + TROWS - 1) / TROWS;
    for (int l = 0; l < L; ++l) {
        graph_side<<<G, D, 0, stream>>>(hcur, nstart, cvec, W + (long)l * D * D,
                                        Wc + (long)l * D * D, b + (long)l * D, T);
        unsigned* hnext = bufs[l & 1];
        layer_kernel<<<layerBlocks, 256, 0, stream>>>(hcur, Wpk + (size_t)l * 2048, T,
                                                      gids, rowptr, csr,
                                                      eps + l, hnext, N);
        hcur = hnext;
    }

    // readout
    readout<<<G, D, 0, stream>>>(hcur, nstart, fc1_w, fc1_b, fc2_w, fc2_b, out);
}